// Round 5
// baseline (4192.092 us; speedup 1.0000x reference)
//
#include <hip/hip_runtime.h>
#include <stdint.h>

// ---------------------------------------------------------------------------
// TSCluster: 3x TransformerEncoderLayer (post-norm, relu) + cluster softmax +
// sequential HMM recursion.  N*P=131072 tokens, D=512, H=8, DFF=2048, C=32.
// bf16 activations + bf16 MFMA GEMMs (f32 accum), f32 LN/softmax.
// GEMM: 256x256 tile, BK=64, FOUR waves (wave tile 128x128, acc 256 VGPR),
// 2-phase/K-tile counted-vmcnt pipeline, XOR-swizzled LDS, LDS-roundtrip
// coalesced epilogue.  Rationale: LDS-pipe-bound before; 4x128x128 waves cut
// fragment-read traffic 1.5x per FLOP.
// ---------------------------------------------------------------------------

typedef __bf16 bf16;
typedef __bf16 bf16x2 __attribute__((ext_vector_type(2)));
typedef __bf16 bf16x4 __attribute__((ext_vector_type(4)));
typedef __bf16 bf16x8 __attribute__((ext_vector_type(8)));
typedef float  f32x4  __attribute__((ext_vector_type(4)));
typedef float  f32x2  __attribute__((ext_vector_type(2)));

#define EPSF 1e-10f
#define NROWS 131072L   // N*P

__device__ __forceinline__ float bflo(uint32_t u){ return __uint_as_float(u << 16); }
__device__ __forceinline__ float bfhi(uint32_t u){ return __uint_as_float(u & 0xffff0000u); }

__device__ __forceinline__ void gload_lds16(const bf16* g, bf16* l){
  __builtin_amdgcn_global_load_lds((const __attribute__((address_space(1))) uint32_t*)g,
                                   (__attribute__((address_space(3))) uint32_t*)l,
                                   16, 0, 0);
}

// ---------------------------------------------------------------------------
__global__ void k_f2bf(const float* __restrict__ in, bf16* __restrict__ out, long n){
  const long stride = (long)gridDim.x * blockDim.x * 4;
  for (long i = ((long)blockIdx.x * blockDim.x + threadIdx.x) * 4; i < n; i += stride){
    f32x4 v = *(const f32x4*)(in + i);
    bf16x4 o = { (bf16)v[0], (bf16)v[1], (bf16)v[2], (bf16)v[3] };
    *(bf16x4*)(out + i) = o;
  }
}

// ---------------------------------------------------------------------------
// 256x256x64 4-wave GEMM: C[m,n] = A[m,k] * W[n,k] + bias[n]  (both K-contig)
// Wave tile 128x128 (2M x 2N wave grid).  Per K-tile: P0 reads A-half0 + all
// B (24 b128), 64 MFMA; P1 reads A-half1 (8 b128), 64 MFMA.  Staging of tile
// t+1: P0 issues A-half0(4) + B(8), P1 issues A-half1(4); waits 12/4.

#define MFMA_BLK(IB)                                                          \
  {                                                                           \
    __builtin_amdgcn_s_setprio(1);                                            \
    _Pragma("unroll")                                                         \
    for (int kk = 0; kk < 2; kk++) {                                          \
      _Pragma("unroll")                                                       \
      for (int i2 = 0; i2 < 4; i2++) {                                        \
        _Pragma("unroll")                                                     \
        for (int j2 = 0; j2 < 8; j2++) {                                      \
          acc[(IB)*4+i2][j2] = __builtin_amdgcn_mfma_f32_16x16x32_bf16(       \
              a[i2][kk], b[j2][kk], acc[(IB)*4+i2][j2], 0, 0, 0);             \
        }                                                                     \
      }                                                                       \
    }                                                                         \
    __builtin_amdgcn_s_setprio(0);                                            \
  }

#define RD_A(RH)                                                              \
  _Pragma("unroll")                                                           \
  for (int i2 = 0; i2 < 4; i2++) {                                            \
    a[i2][0] = *(const bf16x8*)&Ac[aOff + ((RH)*4 + i2)*1024 + sl0];          \
    a[i2][1] = *(const bf16x8*)&Ac[aOff + ((RH)*4 + i2)*1024 + sl1];          \
  }

#define RD_B_ALL                                                              \
  _Pragma("unroll")                                                           \
  for (int j2 = 0; j2 < 8; j2++) {                                            \
    b[j2][0] = *(const bf16x8*)&Bc[bOff + j2*1024 + sl0];                     \
    b[j2][1] = *(const bf16x8*)&Bc[bOff + j2*1024 + sl1];                     \
  }

#define ISSUE_A(dst, C, KK) \
  gload_lds16(gA + (long)(C)*8*lda + (KK), (dst) + (C)*512)
#define ISSUE_B(dst, C, KK) \
  gload_lds16(gB + (long)(C)*8*K   + (KK), (dst) + (C)*512)

#define WAITV(N)  asm volatile("s_waitcnt vmcnt(" #N ")" ::: "memory")
#define WAITL0    asm volatile("s_waitcnt lgkmcnt(0)" ::: "memory")
#define BARRIER   { __builtin_amdgcn_s_barrier(); asm volatile("" ::: "memory"); }

template<int RELU>
__global__ __launch_bounds__(256, 1)
void gemm256(const bf16* __restrict__ A, long lda,
             const bf16* __restrict__ W,
             const float* __restrict__ bias,
             bf16* __restrict__ Cb, long K, int nbx)
{
  const int tid  = threadIdx.x;
  const int wid  = tid >> 6;
  const int lane = tid & 63;
  const int wr = wid >> 1, wc = wid & 1;
  const long ldc = (long)nbx * 256;

  // XCD-chunked block swizzle (nwg % 8 == 0 for all our shapes)
  const unsigned nwg = gridDim.x;
  const unsigned q   = nwg >> 3;
  const unsigned swz = (blockIdx.x & 7) * q + (blockIdx.x >> 3);
  const unsigned bx  = swz % (unsigned)nbx;
  const unsigned by  = swz / (unsigned)nbx;
  const long bm = (long)by * 256;
  const long bn = (long)bx * 256;

  __shared__ __align__(16) bf16 smem[65536];   // 128 KiB
  bf16* const As0 = smem;
  bf16* const Bs0 = smem + 16384;
  bf16* const As1 = smem + 32768;
  bf16* const Bs1 = smem + 49152;

  // staging: 1KB chunk = 8 rows x 64 k; lane l -> row l>>3, granule (l&7)
  const int gsrc = ((lane & 7) ^ ((lane >> 3) & 7)) * 8;   // inverse swizzle
  const bf16* gA = A + (bm + (lane >> 3)) * lda + gsrc;
  const bf16* gB = W + (bn + (lane >> 3)) * K   + gsrc;

  // chunk assignment (A: 32 chunks; half0-needed = {0-7,16-23}, half1 = +8;
  //                   B: 32 chunks, all needed in P0)
  const int cA0[4] = { 2*wid, 2*wid + 1, 16 + 2*wid, 17 + 2*wid };
  const int cA1[4] = { 8 + 2*wid, 9 + 2*wid, 24 + 2*wid, 25 + 2*wid };

  // fragment-read constants
  const int fr = lane & 15, fg = lane >> 4;
  const int aOff = (wr * 128 + fr) * 64;
  const int bOff = (wc * 128 + fr) * 64;
  const int sl0 = ((0 + fg) ^ (fr & 7)) * 8;
  const int sl1 = ((4 + fg) ^ (fr & 7)) * 8;

  f32x4 acc[8][8];
#pragma unroll
  for (int i = 0; i < 8; i++)
#pragma unroll
    for (int j = 0; j < 8; j++) acc[i][j] = (f32x4){0.f, 0.f, 0.f, 0.f};

  bf16x8 a[4][2];
  bf16x8 b[8][2];

  const int nt = (int)(K >> 6);

  // ---- prologue: stage tile 0; P0-group(12) then P1-group(4) ----
#pragma unroll
  for (int u = 0; u < 4; u++) ISSUE_A(As0, cA0[u], 0);
#pragma unroll
  for (int u = 0; u < 8; u++) ISSUE_B(Bs0, 8*wid + u, 0);
#pragma unroll
  for (int u = 0; u < 4; u++) ISSUE_A(As0, cA1[u], 0);
  WAITV(4);          // P0-group landed; A-half1 may float
  BARRIER;

  for (int t = 0; t < nt; t++){
    bf16* const Ac = (t & 1) ? As1 : As0;
    bf16* const Bc = (t & 1) ? Bs1 : Bs0;
    bf16* const An = (t & 1) ? As0 : As1;
    bf16* const Bn = (t & 1) ? Bs0 : Bs1;
    const bool stage = (t + 1 < nt);
    const long kn = (long)(t + 1) << 6;

    // ---- phase 0: A rows half-0, all B cols ----
    RD_A(0); RD_B_ALL;
    if (stage){
#pragma unroll
      for (int u = 0; u < 4; u++) ISSUE_A(An, cA0[u], kn);
#pragma unroll
      for (int u = 0; u < 8; u++) ISSUE_B(Bn, 8*wid + u, kn);
    }
    MFMA_BLK(0);
    if (stage){ WAITV(12); } else { WAITV(0); }   // A-half1(t) landed
    BARRIER;

    // ---- phase 1: A rows half-1 ----
    RD_A(1);
    if (stage){
#pragma unroll
      for (int u = 0; u < 4; u++) ISSUE_A(An, cA1[u], kn);
    }
    MFMA_BLK(1);
    if (stage){ WAITV(4); } else { WAITV(0); }    // P0-group(t+1) landed
    BARRIER;
  }

  // ---- epilogue: coalesced C-write via per-wave bf16 LDS roundtrip ----
  // wave slice [32][136] bf16 (8.5 KB); strip = 128x128.
  bf16* const cw = smem + wid * 4352;
  const long r0 = bm + wr * 128;
  const long c0 = bn + wc * 128;
  float bv[8];
#pragma unroll
  for (int j = 0; j < 8; j++) bv[j] = bias[c0 + j * 16 + fr];

#pragma unroll
  for (int ch = 0; ch < 4; ch++){     // 32-row chunks of the 128x128 strip
#pragma unroll
    for (int i2 = 0; i2 < 2; i2++){
      const int i = ch * 2 + i2;
#pragma unroll
      for (int j = 0; j < 8; j++){
#pragma unroll
        for (int r = 0; r < 4; r++){
          float v = acc[i][j][r] + bv[j];
          if (RELU) v = fmaxf(v, 0.f);
          cw[(i2 * 16 + fg * 4 + r) * 136 + j * 16 + fr] = (bf16)v;
        }
      }
    }
    WAITL0;   // wave-local: ds_writes visible to own lanes' reads
#pragma unroll
    for (int p = 0; p < 8; p++){
      const int row = p * 4 + fg;
      bf16x8 o = *(const bf16x8*)&cw[row * 136 + fr * 8];
      *(bf16x8*)&Cb[(r0 + ch * 32 + row) * ldc + c0 + fr * 8] = o;
    }
    WAITL0;   // reads done before next chunk overwrites the slice
  }
}

// ---------------------------------------------------------------------------
// Fused attention for one (n, h): Q,K,V are 64x64 bf16 slices of the qkv buffer
// [NROWS][1536].  O overwrites the Q slice.  scale = 1/sqrt(64) = 0.125.
__global__ __launch_bounds__(256)
void attention(bf16* __restrict__ qkv)
{
  const int blk = blockIdx.x;
  const long n = blk >> 3;
  const int h  = blk & 7;
  const int tid = threadIdx.x;
  const int wid = tid >> 6, lane = tid & 63;

  __shared__ __align__(16) bf16 Qs[64][72];
  __shared__ __align__(16) bf16 Ks[64][72];
  __shared__ __align__(16) bf16 Vt[64][72];

  bf16* base = qkv + n * 64 * 1536 + h * 64;

  for (int c = tid; c < 512; c += 256){
    const int row = c >> 3, col = (c & 7) * 8;
    const long go = (long)row * 1536 + col;
    *(bf16x8*)&Qs[row][col] = *(const bf16x8*)(base + go);
    *(bf16x8*)&Ks[row][col] = *(const bf16x8*)(base + 512 + go);
    bf16x8 v = *(const bf16x8*)(base + 1024 + go);
#pragma unroll
    for (int e = 0; e < 8; e++) Vt[col + e][row] = v[e];
  }
  __syncthreads();

  const int fr = lane & 15, fg = lane >> 4;
  f32x4 sacc[4];
#pragma unroll
  for (int j = 0; j < 4; j++) sacc[j] = (f32x4){0.f, 0.f, 0.f, 0.f};
#pragma unroll
  for (int ks = 0; ks < 2; ks++){
    bf16x8 aa = *(const bf16x8*)&Qs[wid * 16 + fr][ks * 32 + fg * 8];
#pragma unroll
    for (int j = 0; j < 4; j++){
      bf16x8 bb = *(const bf16x8*)&Ks[j * 16 + fr][ks * 32 + fg * 8];
      sacc[j] = __builtin_amdgcn_mfma_f32_16x16x32_bf16(aa, bb, sacc[j], 0, 0, 0);
    }
  }

  float pv[4][4];
#pragma unroll
  for (int r = 0; r < 4; r++){
    float m = -1e30f;
#pragma unroll
    for (int j = 0; j < 4; j++) m = fmaxf(m, sacc[j][r]);
#pragma unroll
    for (int msk = 1; msk < 16; msk <<= 1) m = fmaxf(m, __shfl_xor(m, msk));
    float s = 0.f;
#pragma unroll
    for (int j = 0; j < 4; j++){
      float p = __expf((sacc[j][r] - m) * 0.125f);
      pv[j][r] = p; s += p;
    }
#pragma unroll
    for (int msk = 1; msk < 16; msk <<= 1) s += __shfl_xor(s, msk);
    const float inv = 1.f / s;
#pragma unroll
    for (int j = 0; j < 4; j++) pv[j][r] *= inv;
  }

#pragma unroll
  for (int j = 0; j < 4; j++)
#pragma unroll
    for (int r = 0; r < 4; r++)
      Qs[wid * 16 + fg * 4 + r][j * 16 + fr] = (bf16)pv[j][r];
  __syncthreads();

  f32x4 oacc[4];
#pragma unroll
  for (int j = 0; j < 4; j++) oacc[j] = (f32x4){0.f, 0.f, 0.f, 0.f};
#pragma unroll
  for (int ks = 0; ks < 2; ks++){
    bf16x8 aa = *(const bf16x8*)&Qs[wid * 16 + fr][ks * 32 + fg * 8];
#pragma unroll
    for (int j = 0; j < 4; j++){
      bf16x8 bb = *(const bf16x8*)&Vt[j * 16 + fr][ks * 32 + fg * 8];
      oacc[j] = __builtin_amdgcn_mfma_f32_16x16x32_bf16(aa, bb, oacc[j], 0, 0, 0);
    }
  }
#pragma unroll
  for (int j = 0; j < 4; j++)
#pragma unroll
    for (int r = 0; r < 4; r++)
      base[(long)(wid * 16 + fg * 4 + r) * 1536 + j * 16 + fr] = (bf16)oacc[j][r];
}

// ---------------------------------------------------------------------------
// y = LayerNorm(x + o) * w + b ; one WAVE per row, 4 rows/block, no LDS.
// Optionally also writes the f32 result to EF (fused emb_ts output).
__global__ __launch_bounds__(256)
void resid_ln(const bf16* __restrict__ X, const bf16* __restrict__ O,
              const float* __restrict__ w, const float* __restrict__ b,
              bf16* __restrict__ Y, float* __restrict__ EF)
{
  const int wid = threadIdx.x >> 6, lane = threadIdx.x & 63;
  const long row = (long)blockIdx.x * 4 + wid;
  const uint4 xu = ((const uint4*)(X + row * 512))[lane];
  const uint4 ou = ((const uint4*)(O + row * 512))[lane];
  float s[8];
  s[0] = bflo(xu.x) + bflo(ou.x);  s[1] = bfhi(xu.x) + bfhi(ou.x);
  s[2] = bflo(xu.y) + bflo(ou.y);  s[3] = bfhi(xu.y) + bfhi(ou.y);
  s[4] = bflo(xu.z) + bflo(ou.z);  s[5] = bfhi(xu.z) + bfhi(ou.z);
  s[6] = bflo(xu.w) + bflo(ou.w);  s[7] = bfhi(xu.w) + bfhi(ou.w);
  float sum = 0.f, sq = 0.f;
#pragma unroll
  for (int e = 0; e < 8; e++){ sum += s[e]; sq += s[e] * s[e]; }
#pragma unroll
  for (int m = 1; m < 64; m <<= 1){ sum += __shfl_xor(sum, m); sq += __shfl_xor(sq, m); }
  const float mean = sum * (1.f / 512.f);
  const float var  = sq * (1.f / 512.f) - mean * mean;
  const float rs   = rsqrtf(var + 1e-5f);
  const f32x4 w0 = *(const f32x4*)(w + 8 * lane);
  const f32x4 w1 = *(const f32x4*)(w + 8 * lane + 4);
  const f32x4 b0 = *(const f32x4*)(b + 8 * lane);
  const f32x4 b1 = *(const f32x4*)(b + 8 * lane + 4);
  float o[8];
#pragma unroll
  for (int e = 0; e < 4; e++) o[e]     = (s[e]     - mean) * rs * w0[e] + b0[e];
#pragma unroll
  for (int e = 0; e < 4; e++) o[e + 4] = (s[e + 4] - mean) * rs * w1[e] + b1[e];
  bf16x8 ov = { (bf16)o[0], (bf16)o[1], (bf16)o[2], (bf16)o[3],
                (bf16)o[4], (bf16)o[5], (bf16)o[6], (bf16)o[7] };
  *(bf16x8*)(Y + row * 512 + 8 * lane) = ov;
  if (EF){
    f32x4 e0 = { o[0], o[1], o[2], o[3] };
    f32x4 e1 = { o[4], o[5], o[6], o[7] };
    *(f32x4*)(EF + row * 512 + 8 * lane) = e0;
    *(f32x4*)(EF + row * 512 + 8 * lane + 4) = e1;
  }
}

// ---------------------------------------------------------------------------
__global__ __launch_bounds__(256)
void k_mu(const float* __restrict__ mus, bf16* __restrict__ mubf, float* __restrict__ munorm)
{
  const int c = blockIdx.x, tid = threadIdx.x, lane = tid & 63, wid = tid >> 6;
  const f32x2 v = *(const f32x2*)(mus + c * 512 + 2 * tid);
  const float t0 = tanhf(v[0]), t1 = tanhf(v[1]);
  bf16x2 o2 = { (bf16)t0, (bf16)t1 };
  *(bf16x2*)(mubf + c * 512 + 2 * tid) = o2;
  float sq = t0 * t0 + t1 * t1;
#pragma unroll
  for (int m = 1; m < 64; m <<= 1) sq += __shfl_xor(sq, m);
  __shared__ float red[4];
  if (lane == 0) red[wid] = sq;
  __syncthreads();
  if (tid == 0) munorm[c] = red[0] + red[1] + red[2] + red[3];
}

// ---------------------------------------------------------------------------
__global__ __launch_bounds__(256)
void cluster_logza(const bf16* __restrict__ X, const bf16* __restrict__ MU,
                   const float* __restrict__ munorm, float* __restrict__ out)
{
  const int tid = threadIdx.x, lane = tid & 63, wid = tid >> 6;
  __shared__ __align__(16) bf16 mus[32][512];
  __shared__ float xs[512];
  __shared__ float red[4];
  __shared__ float dots[32];
  for (int c = tid; c < 2048; c += 256){
    const int r = c >> 6, col = (c & 63) * 8;
    *(bf16x8*)&mus[r][col] = *(const bf16x8*)(MU + r * 512 + col);
  }
  const int cc = tid >> 3, seg = tid & 7;
  const long row0 = (long)blockIdx.x * 16;
  __syncthreads();
  for (int rr = 0; rr < 16; rr++){
    const long row = row0 + rr;
    const uint32_t u = ((const uint32_t*)(X + row * 512))[tid];
    const float aa = bflo(u), bb = bfhi(u);
    xs[2 * tid] = aa; xs[2 * tid + 1] = bb;
    float sq = aa * aa + bb * bb;
#pragma unroll
    for (int m = 1; m < 64; m <<= 1) sq += __shfl_xor(sq, m);
    if (lane == 0) red[wid] = sq;
    __syncthreads();
    const float xn = red[0] + red[1] + red[2] + red[3];
    float p = 0.f;
#pragma unroll
    for (int jj = 0; jj < 8; jj++){
      const int col = jj * 64 + seg * 8;
      bf16x8 m8 = *(const bf16x8*)&mus[cc][col];
      const float* xv = &xs[col];
#pragma unroll
      for (int e = 0; e < 8; e++) p += xv[e] * (float)m8[e];
    }
#pragma unroll
    for (int m = 1; m < 8; m <<= 1) p += __shfl_xor(p, m);
    if (seg == 0) dots[cc] = p;
    __syncthreads();
    if (tid < 32){
      const float dist = xn + munorm[tid] - 2.f * dots[tid];
      const float lg = -dist * 0.1f;
      float mx = lg;
#pragma unroll
      for (int m = 1; m < 32; m <<= 1) mx = fmaxf(mx, __shfl_xor(mx, m, 32));
      const float z = __expf(lg - mx);
      float s = z;
#pragma unroll
      for (int m = 1; m < 32; m <<= 1) s += __shfl_xor(s, m, 32);
      out[row * 32 + tid] = logf(z / s + EPSF);
    }
    __syncthreads();
  }
}

// ---------------------------------------------------------------------------
__global__ __launch_bounds__(256)
void k_hmm(const float* __restrict__ lza, const float* __restrict__ pi,
           const float* __restrict__ A, float* __restrict__ cp, float* __restrict__ ent)
{
  __shared__ float As[32][33];
  const int tid = threadIdx.x;
  for (int i = tid; i < 1024; i += 256) As[i >> 5][i & 31] = A[i];
  __syncthreads();
  const int j = tid & 31;
  const long n = (long)blockIdx.x * 8 + (tid >> 5);
  const float* lz = lza + n * 2048;

  float c = logf(pi[j] + EPSF) + lz[j];
  {
    float mx = c;
#pragma unroll
    for (int m = 1; m < 32; m <<= 1) mx = fmaxf(mx, __shfl_xor(mx, m, 32));
    float z = __expf(c - mx), s = z;
#pragma unroll
    for (int m = 1; m < 32; m <<= 1) s += __shfl_xor(s, m, 32);
    c = z / s;
  }
  cp[n * 2048 + j] = c;
  float ea = -c * logf(c + EPSF);

  for (int p = 1; p < 64; p++){
    float y = 0.f;
#pragma unroll
    for (int i = 0; i < 32; i++) y += __shfl(c, i, 32) * As[i][j];
    float t = logf(y + EPSF) + lz[p * 32 + j];
    float mx = t;
#pragma unroll
    for (int m = 1; m < 32; m <<= 1) mx = fmaxf(mx, __shfl_xor(mx, m, 32));
    float z = __expf(t - mx), s = z;
#pragma unroll
    for (int m = 1; m < 32; m <<= 1) s += __shfl_xor(s, m, 32);
    c = z / s;
    cp[n * 2048 + p * 32 + j] = c;
    ea += -c * logf(c + EPSF);
  }
#pragma unroll
  for (int m = 1; m < 32; m <<= 1) ea += __shfl_xor(ea, m, 32);
  if (j == 0) atomicAdd(ent, ea * (1.f / 131072.f));
}

// ---------------------------------------------------------------------------
extern "C" void kernel_launch(void* const* d_in, const int* in_sizes, int n_in,
                              void* d_out, int out_size, void* d_ws, size_t ws_size,
                              hipStream_t stream)
{
  (void)in_sizes; (void)n_in; (void)out_size; (void)ws_size;
  const float* in_series = (const float*)d_in[0];
  const float* pi    = (const float*)d_in[1];
  const float* Amat  = (const float*)d_in[2];
  const float* qkv_w = (const float*)d_in[3];
  const float* qkv_b = (const float*)d_in[4];
  const float* out_w = (const float*)d_in[5];
  const float* out_b = (const float*)d_in[6];
  const float* ln1_w = (const float*)d_in[7];
  const float* ln1_b = (const float*)d_in[8];
  const float* ff1_w = (const float*)d_in[9];
  const float* ff1_b = (const float*)d_in[10];
  const float* ff2_w = (const float*)d_in[11];
  const float* ff2_b = (const float*)d_in[12];
  const float* ln2_w = (const float*)d_in[13];
  const float* ln2_b = (const float*)d_in[14];
  const float* mus   = (const float*)d_in[15];

  char* ws = (char*)d_ws;
  bf16* region0 = (bf16*)(ws);                         // 512MB: qkv / ffmid
  bf16* xb      = (bf16*)(ws + 536870912L);            // 128MB
  bf16* oproj   = (bf16*)(ws + 671088640L);            // 128MB
  bf16* w_qkv   = (bf16*)(ws + 805306368L);
  bf16* w_out   = (bf16*)(ws + 810024960L);
  bf16* w_ff1   = (bf16*)(ws + 811597824L);
  bf16* w_ff2   = (bf16*)(ws + 817889280L);
  bf16* mubf    = (bf16*)(ws + 824180736L);
  float* munorm = (float*)(ws + 824213504L);
  float* logza  = (float*)(ws);                        // aliases region0

  float* out_f = (float*)d_out;
  float* cp    = out_f;
  float* emb   = out_f + 4194304L;
  float* o_pi  = out_f + 71303168L;
  float* o_A   = out_f + 71303200L;
  float* o_ent = out_f + 71304224L;

  k_f2bf<<<8192, 256, 0, stream>>>(in_series, xb, 67108864L);
  k_f2bf<<<1024, 256, 0, stream>>>(qkv_w, w_qkv, 2359296L);
  k_f2bf<<<1024, 256, 0, stream>>>(out_w, w_out, 786432L);
  k_f2bf<<<1024, 256, 0, stream>>>(ff1_w, w_ff1, 3145728L);
  k_f2bf<<<1024, 256, 0, stream>>>(ff2_w, w_ff2, 3145728L);
  k_mu<<<32, 256, 0, stream>>>(mus, mubf, munorm);

  for (int l = 0; l < 3; l++){
    // qkv = x @ qkv_w^T + b   -> region0 [131072][1536]
    gemm256<0><<<3072, 256, 0, stream>>>(xb, 512, w_qkv + (long)l * 786432L,
                                         qkv_b + (long)l * 1536, region0, 512, 6);
    attention<<<16384, 256, 0, stream>>>(region0);
    // o @ out_w^T + b -> oproj
    gemm256<0><<<1024, 256, 0, stream>>>(region0, 1536, w_out + (long)l * 262144L,
                                         out_b + (long)l * 512, oproj, 512, 2);
    resid_ln<<<32768, 256, 0, stream>>>(xb, oproj, ln1_w + (long)l * 512,
                                        ln1_b + (long)l * 512, xb, nullptr);
    // ffmid = relu(x @ ff1_w^T + b) -> region0 [131072][2048]
    gemm256<1><<<4096, 256, 0, stream>>>(xb, 512, w_ff1 + (long)l * 1048576L,
                                         ff1_b + (long)l * 2048, region0, 512, 8);
    // ffout = ffmid @ ff2_w^T + b -> oproj
    gemm256<0><<<1024, 256, 0, stream>>>(region0, 2048, w_ff2 + (long)l * 1048576L,
                                         ff2_b + (long)l * 512, oproj, 2048, 2);
    // last layer: fuse f32 emb_ts output into the LN
    resid_ln<<<32768, 256, 0, stream>>>(xb, oproj, ln2_w + (long)l * 512,
                                        ln2_b + (long)l * 512, xb,
                                        (l == 2) ? emb : nullptr);
  }

  cluster_logza<<<8192, 256, 0, stream>>>(xb, mubf, munorm, logza);
  hipMemsetAsync(o_ent, 0, 4, stream);
  k_hmm<<<256, 256, 0, stream>>>(logza, pi, Amat, cp, o_ent);
  hipMemcpyAsync(o_pi, pi, 32 * sizeof(float), hipMemcpyDeviceToDevice, stream);
  hipMemcpyAsync(o_A, Amat, 1024 * sizeof(float), hipMemcpyDeviceToDevice, stream);
}

// Round 7
// 3934.406 us; speedup vs baseline: 1.0655x; 1.0655x over previous
//
#include <hip/hip_runtime.h>
#include <stdint.h>

// ---------------------------------------------------------------------------
// TSCluster: 3x TransformerEncoderLayer (post-norm, relu) + cluster softmax +
// sequential HMM recursion.  N*P=131072 tokens, D=512, H=8, DFF=2048, C=32.
// bf16 activations + bf16 MFMA GEMMs (f32 accum), f32 LN/softmax.
// GEMM: 256x256 tile, BK=64, 8 waves, 4-phase progressive-half schedule.
// R6 race fixed: B1(t)/A1(t) landing is now guaranteed by WAITV(6) at the END
// of phase 1 (before its barrier), so phase-2/3 ds_reads are covered both
// intra-wave (program order) and cross-wave (barrier after every wave waits).
// ---------------------------------------------------------------------------

typedef __bf16 bf16;
typedef __bf16 bf16x2 __attribute__((ext_vector_type(2)));
typedef __bf16 bf16x4 __attribute__((ext_vector_type(4)));
typedef __bf16 bf16x8 __attribute__((ext_vector_type(8)));
typedef float  f32x4  __attribute__((ext_vector_type(4)));
typedef float  f32x2  __attribute__((ext_vector_type(2)));

#define EPSF 1e-10f
#define NROWS 131072L   // N*P

__device__ __forceinline__ float bflo(uint32_t u){ return __uint_as_float(u << 16); }
__device__ __forceinline__ float bfhi(uint32_t u){ return __uint_as_float(u & 0xffff0000u); }

__device__ __forceinline__ void gload_lds16(const bf16* g, bf16* l){
  __builtin_amdgcn_global_load_lds((const __attribute__((address_space(1))) uint32_t*)g,
                                   (__attribute__((address_space(3))) uint32_t*)l,
                                   16, 0, 0);
}

// ---------------------------------------------------------------------------
__global__ void k_f2bf(const float* __restrict__ in, bf16* __restrict__ out, long n){
  const long stride = (long)gridDim.x * blockDim.x * 4;
  for (long i = ((long)blockIdx.x * blockDim.x + threadIdx.x) * 4; i < n; i += stride){
    f32x4 v = *(const f32x4*)(in + i);
    bf16x4 o = { (bf16)v[0], (bf16)v[1], (bf16)v[2], (bf16)v[3] };
    *(bf16x4*)(out + i) = o;
  }
}

// ---------------------------------------------------------------------------
// 256x256x64 8-wave GEMM: C[m,n] = A[m,k] * W[n,k] + bias[n]  (both K-contig)
// Wave output: rows {wr*64+[0,64)} u {128+wr*64+[0,64)},
//              cols {wc*32+[0,32)} u {128+wc*32+[0,32)}  (wr 0-1, wc 0-3)
// Phases: (m0,n0) (m0,n1) (m1,n0) (m1,n1); a-frags per m-strip, b both held.
//
// Wait ledger (steady state, per wave; issues: P1 +A1(t+1), P2 +B1(t+1),
// P3 +A0(t+2), P4 +B0(t+2); outstanding 8->10->8->10->12->8):
//   P1 end WAITV(6):  retires A1(t),B1(t)   -> P2 RD_B(1), P3 RD_A(1) safe
//   P4 end WAITV(8):  retires A0(t+1),B0(t+1) -> next P1 reads safe
// tails: penultimate P4 WAITV(4); last tile P1 WAITV(0).

#define MFMA_PH(SM, SN)                                                       \
  {                                                                           \
    __builtin_amdgcn_s_setprio(1);                                            \
    _Pragma("unroll")                                                         \
    for (int kk = 0; kk < 2; kk++) {                                          \
      _Pragma("unroll")                                                       \
      for (int i2 = 0; i2 < 4; i2++) {                                        \
        _Pragma("unroll")                                                     \
        for (int j2 = 0; j2 < 2; j2++) {                                      \
          acc[(SM)*4+i2][(SN)*2+j2] = __builtin_amdgcn_mfma_f32_16x16x32_bf16(\
              a[i2][kk], b[SN][j2][kk], acc[(SM)*4+i2][(SN)*2+j2], 0, 0, 0);  \
        }                                                                     \
      }                                                                       \
    }                                                                         \
    __builtin_amdgcn_s_setprio(0);                                            \
  }

#define RD_A(SM)                                                              \
  _Pragma("unroll")                                                           \
  for (int i2 = 0; i2 < 4; i2++) {                                            \
    a[i2][0] = *(const bf16x8*)&Ac[(SM)*8192 + aBase + i2*1024 + sl0];        \
    a[i2][1] = *(const bf16x8*)&Ac[(SM)*8192 + aBase + i2*1024 + sl1];        \
  }

#define RD_B(SN)                                                              \
  _Pragma("unroll")                                                           \
  for (int j2 = 0; j2 < 2; j2++) {                                            \
    b[SN][j2][0] = *(const bf16x8*)&Bc[(SN)*8192 + bBase + j2*1024 + sl0];    \
    b[SN][j2][1] = *(const bf16x8*)&Bc[(SN)*8192 + bBase + j2*1024 + sl1];    \
  }

// one ISSUE = 64 rows x 64 k staged by 512 threads (8 rows per wave)
#define ISSUE_A(dst, RO, KK) \
  gload_lds16(gA + (long)(RO)*lda + (KK), (dst) + (RO)*64 + wsl)
#define ISSUE_B(dst, RO, KK) \
  gload_lds16(gB + (long)(RO)*K   + (KK), (dst) + (RO)*64 + wsl)

#define WAITV(N)  asm volatile("s_waitcnt vmcnt(" #N ")" ::: "memory")
#define WAITL0    asm volatile("s_waitcnt lgkmcnt(0)" ::: "memory")
#define BARRIER   { __builtin_amdgcn_s_barrier(); asm volatile("" ::: "memory"); }

template<int RELU>
__global__ __launch_bounds__(512, 2)
void gemm256(const bf16* __restrict__ A, long lda,
             const bf16* __restrict__ W,
             const float* __restrict__ bias,
             bf16* __restrict__ Cb, long K, int nbx)
{
  const int tid  = threadIdx.x;
  const int wid  = tid >> 6;
  const int lane = tid & 63;
  const int wr = wid >> 2, wc = wid & 3;
  const long ldc = (long)nbx * 256;

  // XCD-chunked block swizzle (nwg % 8 == 0 for all our shapes)
  const unsigned nwg = gridDim.x;
  const unsigned q   = nwg >> 3;
  const unsigned swz = (blockIdx.x & 7) * q + (blockIdx.x >> 3);
  const unsigned bx  = swz % (unsigned)nbx;
  const unsigned by  = swz / (unsigned)nbx;
  const long bm = (long)by * 256;
  const long bn = (long)bx * 256;

  __shared__ __align__(16) bf16 smem[65536];   // 128 KiB
  bf16* const As0 = smem;
  bf16* const Bs0 = smem + 16384;
  bf16* const As1 = smem + 32768;
  bf16* const Bs1 = smem + 49152;

  // staging: per issue, wave w covers rows RO + w*8 .. +8; granule XOR swizzle
  const int gswz = ((lane & 7) ^ ((lane >> 3) & 7)) * 8;   // inverse swizzle
  const int wsl  = wid * 512;
  const bf16* gA = A + (bm + wid * 8 + (lane >> 3)) * lda + gswz;
  const bf16* gB = W + (bn + wid * 8 + (lane >> 3)) * K   + gswz;

  // fragment-read constants
  const int fr = lane & 15, fg = lane >> 4;
  const int aBase = (wr * 64 + fr) * 64;
  const int bBase = (wc * 32 + fr) * 64;
  const int sl0 = ((0 + fg) ^ (fr & 7)) * 8;
  const int sl1 = ((4 + fg) ^ (fr & 7)) * 8;

  f32x4 acc[8][4];
#pragma unroll
  for (int i = 0; i < 8; i++)
#pragma unroll
    for (int j = 0; j < 4; j++) acc[i][j] = (f32x4){0.f, 0.f, 0.f, 0.f};

  bf16x8 a[4][2];
  bf16x8 b[2][2][2];

  const int nt = (int)(K >> 6);

  // ---- prologue: tile0 {A0,B0,A1,B1} + tile1 {A0,B0}; keep 8 in flight ----
  ISSUE_A(As0, 0, 0);   ISSUE_A(As0, 64, 0);     // A0(t0)
  ISSUE_B(Bs0, 0, 0);   ISSUE_B(Bs0, 64, 0);     // B0(t0)
  ISSUE_A(As0, 128, 0); ISSUE_A(As0, 192, 0);    // A1(t0)
  ISSUE_B(Bs0, 128, 0); ISSUE_B(Bs0, 192, 0);    // B1(t0)
  if (nt > 1){
    ISSUE_A(As1, 0, 64); ISSUE_A(As1, 64, 64);   // A0(t1)
    ISSUE_B(Bs1, 0, 64); ISSUE_B(Bs1, 64, 64);   // B0(t1)
  }
  WAITV(8);        // A0,B0(t0) landed
  BARRIER;

  for (int t = 0; t < nt; t++){
    bf16* const Ac = (t & 1) ? As1 : As0;
    bf16* const Bc = (t & 1) ? Bs1 : Bs0;
    bf16* const An = (t & 1) ? As0 : As1;
    bf16* const Bn = (t & 1) ? Bs0 : Bs1;
    const bool s1 = (t + 1 < nt);       // stage into buf[t+1]
    const bool s2 = (t + 2 < nt);       // stage into buf[t] (freed halves)
    const long kn  = (long)(t + 1) << 6;
    const long kn2 = (long)(t + 2) << 6;

    // ---- phase 1: (m0, n0) -- needs A-half0(t), B-half0(t) ----
    RD_A(0); RD_B(0);
    if (s1){ ISSUE_A(An, 128, kn); ISSUE_A(An, 192, kn); }   // A1(t+1)
    WAITL0;
    MFMA_PH(0, 0);
    if (s1){ WAITV(6); } else { WAITV(0); }   // A1(t),B1(t) landed for P2/P3
    BARRIER;

    // ---- phase 2: (m0, n1) -- needs B-half1(t) (landed at P1 wait) ----
    RD_B(1);
    if (s1){ ISSUE_B(Bn, 128, kn); ISSUE_B(Bn, 192, kn); }   // B1(t+1)
    WAITL0;
    MFMA_PH(0, 1);
    BARRIER;

    // ---- phase 3: (m1, n0) -- needs A-half1(t) (landed at P1 wait) ----
    RD_A(1);
    if (s2){ ISSUE_A(Ac, 0, kn2); ISSUE_A(Ac, 64, kn2); }    // A0(t+2)
    WAITL0;
    MFMA_PH(1, 0);
    BARRIER;

    // ---- phase 4: (m1, n1) ----
    if (s2){ ISSUE_B(Bc, 0, kn2); ISSUE_B(Bc, 64, kn2); }    // B0(t+2)
    MFMA_PH(1, 1);
    if (s2)      { WAITV(8); }     // A0,B0(t+1) landed for next P1
    else if (s1) { WAITV(4); }
    BARRIER;
  }

  // ---- epilogue: per-wave bf16 LDS roundtrip, [32][40] slice (80B rows) ----
  bf16* const cw = smem + wid * 1280;
  float bv[4];
#pragma unroll
  for (int sn = 0; sn < 2; sn++)
#pragma unroll
    for (int j2 = 0; j2 < 2; j2++)
      bv[sn * 2 + j2] = bias[bn + sn * 128 + wc * 32 + j2 * 16 + fr];

#pragma unroll
  for (int sm = 0; sm < 2; sm++){
#pragma unroll
    for (int sn = 0; sn < 2; sn++){
#pragma unroll
      for (int ch = 0; ch < 2; ch++){
#pragma unroll
        for (int i2 = 0; i2 < 2; i2++){
#pragma unroll
          for (int j2 = 0; j2 < 2; j2++){
#pragma unroll
            for (int r = 0; r < 4; r++){
              float v = acc[sm * 4 + ch * 2 + i2][sn * 2 + j2][r] + bv[sn * 2 + j2];
              if (RELU) v = fmaxf(v, 0.f);
              cw[(i2 * 16 + fg * 4 + r) * 40 + j2 * 16 + fr] = (bf16)v;
            }
          }
        }
        WAITL0;   // wave-local: ds_writes visible to own lanes' reads
        const long r0 = bm + sm * 128 + wr * 64 + ch * 32;
        const long c0 = bn + sn * 128 + wc * 32;
#pragma unroll
        for (int p = 0; p < 2; p++){
          const int row = p * 16 + (lane >> 2);
          const int colg = (lane & 3) * 8;
          bf16x8 o = *(const bf16x8*)&cw[row * 40 + colg];
          *(bf16x8*)&Cb[(r0 + row) * ldc + c0 + colg] = o;
        }
        WAITL0;   // reads done before next chunk overwrites the slice
      }
    }
  }
}

// ---------------------------------------------------------------------------
// Fused attention for one (n, h): Q,K,V are 64x64 bf16 slices of the qkv buffer
// [NROWS][1536].  O overwrites the Q slice.  scale = 1/sqrt(64) = 0.125.
__global__ __launch_bounds__(256)
void attention(bf16* __restrict__ qkv)
{
  const int blk = blockIdx.x;
  const long n = blk >> 3;
  const int h  = blk & 7;
  const int tid = threadIdx.x;
  const int wid = tid >> 6, lane = tid & 63;

  __shared__ __align__(16) bf16 Qs[64][72];
  __shared__ __align__(16) bf16 Ks[64][72];
  __shared__ __align__(16) bf16 Vt[64][72];

  bf16* base = qkv + n * 64 * 1536 + h * 64;

  for (int c = tid; c < 512; c += 256){
    const int row = c >> 3, col = (c & 7) * 8;
    const long go = (long)row * 1536 + col;
    *(bf16x8*)&Qs[row][col] = *(const bf16x8*)(base + go);
    *(bf16x8*)&Ks[row][col] = *(const bf16x8*)(base + 512 + go);
    bf16x8 v = *(const bf16x8*)(base + 1024 + go);
#pragma unroll
    for (int e = 0; e < 8; e++) Vt[col + e][row] = v[e];
  }
  __syncthreads();

  const int fr = lane & 15, fg = lane >> 4;
  f32x4 sacc[4];
#pragma unroll
  for (int j = 0; j < 4; j++) sacc[j] = (f32x4){0.f, 0.f, 0.f, 0.f};
#pragma unroll
  for (int ks = 0; ks < 2; ks++){
    bf16x8 aa = *(const bf16x8*)&Qs[wid * 16 + fr][ks * 32 + fg * 8];
#pragma unroll
    for (int j = 0; j < 4; j++){
      bf16x8 bb = *(const bf16x8*)&Ks[j * 16 + fr][ks * 32 + fg * 8];
      sacc[j] = __builtin_amdgcn_mfma_f32_16x16x32_bf16(aa, bb, sacc[j], 0, 0, 0);
    }
  }

  float pv[4][4];
#pragma unroll
  for (int r = 0; r < 4; r++){
    float m = -1e30f;
#pragma unroll
    for (int j = 0; j < 4; j++) m = fmaxf(m, sacc[j][r]);
#pragma unroll
    for (int msk = 1; msk < 16; msk <<= 1) m = fmaxf(m, __shfl_xor(m, msk));
    float s = 0.f;
#pragma unroll
    for (int j = 0; j < 4; j++){
      float p = __expf((sacc[j][r] - m) * 0.125f);
      pv[j][r] = p; s += p;
    }
#pragma unroll
    for (int msk = 1; msk < 16; msk <<= 1) s += __shfl_xor(s, msk);
    const float inv = 1.f / s;
#pragma unroll
    for (int j = 0; j < 4; j++) pv[j][r] *= inv;
  }

#pragma unroll
  for (int j = 0; j < 4; j++)
#pragma unroll
    for (int r = 0; r < 4; r++)
      Qs[wid * 16 + fg * 4 + r][j * 16 + fr] = (bf16)pv[j][r];
  __syncthreads();

  f32x4 oacc[4];
#pragma unroll
  for (int j = 0; j < 4; j++) oacc[j] = (f32x4){0.f, 0.f, 0.f, 0.f};
#pragma unroll
  for (int ks = 0; ks < 2; ks++){
    bf16x8 aa = *(const bf16x8*)&Qs[wid * 16 + fr][ks * 32 + fg * 8];
#pragma unroll
    for (int j = 0; j < 4; j++){
      bf16x8 bb = *(const bf16x8*)&Vt[j * 16 + fr][ks * 32 + fg * 8];
      oacc[j] = __builtin_amdgcn_mfma_f32_16x16x32_bf16(aa, bb, oacc[j], 0, 0, 0);
    }
  }
#pragma unroll
  for (int j = 0; j < 4; j++)
#pragma unroll
    for (int r = 0; r < 4; r++)
      base[(long)(wid * 16 + fg * 4 + r) * 1536 + j * 16 + fr] = (bf16)oacc[j][r];
}

// ---------------------------------------------------------------------------
// y = LayerNorm(x + o) * w + b ; one WAVE per row, 4 rows/block, no LDS.
// Optionally also writes the f32 result to EF (fused emb_ts output).
__global__ __launch_bounds__(256)
void resid_ln(const bf16* __restrict__ X, const bf16* __restrict__ O,
              const float* __restrict__ w, const float* __restrict__ b,
              bf16* __restrict__ Y, float* __restrict__ EF)
{
  const int wid = threadIdx.x >> 6, lane = threadIdx.x & 63;
  const long row = (long)blockIdx.x * 4 + wid;
  const uint4 xu = ((const uint4*)(X + row * 512))[lane];
  const uint4 ou = ((const uint4*)(O + row * 512))[lane];
  float s[8];
  s[0] = bflo(xu.x) + bflo(ou.x);  s[1] = bfhi(xu.x) + bfhi(ou.x);
  s[2] = bflo(xu.y) + bflo(ou.y);  s[3] = bfhi(xu.y) + bfhi(ou.y);
  s[4] = bflo(xu.z) + bflo(ou.z);  s[5] = bfhi(xu.z) + bfhi(ou.z);
  s[6] = bflo(xu.w) + bflo(ou.w);  s[7] = bfhi(xu.w) + bfhi(ou.w);
  float sum = 0.f, sq = 0.f;
#pragma unroll
  for (int e = 0; e < 8; e++){ sum += s[e]; sq += s[e] * s[e]; }
#pragma unroll
  for (int m = 1; m < 64; m <<= 1){ sum += __shfl_xor(sum, m); sq += __shfl_xor(sq, m); }
  const float mean = sum * (1.f / 512.f);
  const float var  = sq * (1.f / 512.f) - mean * mean;
  const float rs   = rsqrtf(var + 1e-5f);
  const f32x4 w0 = *(const f32x4*)(w + 8 * lane);
  const f32x4 w1 = *(const f32x4*)(w + 8 * lane + 4);
  const f32x4 b0 = *(const f32x4*)(b + 8 * lane);
  const f32x4 b1 = *(const f32x4*)(b + 8 * lane + 4);
  float o[8];
#pragma unroll
  for (int e = 0; e < 4; e++) o[e]     = (s[e]     - mean) * rs * w0[e] + b0[e];
#pragma unroll
  for (int e = 0; e < 4; e++) o[e + 4] = (s[e + 4] - mean) * rs * w1[e] + b1[e];
  bf16x8 ov = { (bf16)o[0], (bf16)o[1], (bf16)o[2], (bf16)o[3],
                (bf16)o[4], (bf16)o[5], (bf16)o[6], (bf16)o[7] };
  *(bf16x8*)(Y + row * 512 + 8 * lane) = ov;
  if (EF){
    f32x4 e0 = { o[0], o[1], o[2], o[3] };
    f32x4 e1 = { o[4], o[5], o[6], o[7] };
    *(f32x4*)(EF + row * 512 + 8 * lane) = e0;
    *(f32x4*)(EF + row * 512 + 8 * lane + 4) = e1;
  }
}

// ---------------------------------------------------------------------------
__global__ __launch_bounds__(256)
void k_mu(const float* __restrict__ mus, bf16* __restrict__ mubf, float* __restrict__ munorm)
{
  const int c = blockIdx.x, tid = threadIdx.x, lane = tid & 63, wid = tid >> 6;
  const f32x2 v = *(const f32x2*)(mus + c * 512 + 2 * tid);
  const float t0 = tanhf(v[0]), t1 = tanhf(v[1]);
  bf16x2 o2 = { (bf16)t0, (bf16)t1 };
  *(bf16x2*)(mubf + c * 512 + 2 * tid) = o2;
  float sq = t0 * t0 + t1 * t1;
#pragma unroll
  for (int m = 1; m < 64; m <<= 1) sq += __shfl_xor(sq, m);
  __shared__ float red[4];
  if (lane == 0) red[wid] = sq;
  __syncthreads();
  if (tid == 0) munorm[c] = red[0] + red[1] + red[2] + red[3];
}

// ---------------------------------------------------------------------------
__global__ __launch_bounds__(256)
void cluster_logza(const bf16* __restrict__ X, const bf16* __restrict__ MU,
                   const float* __restrict__ munorm, float* __restrict__ out)
{
  const int tid = threadIdx.x, lane = tid & 63, wid = tid >> 6;
  __shared__ __align__(16) bf16 mus[32][512];
  __shared__ float xs[512];
  __shared__ float red[4];
  __shared__ float dots[32];
  for (int c = tid; c < 2048; c += 256){
    const int r = c >> 6, col = (c & 63) * 8;
    *(bf16x8*)&mus[r][col] = *(const bf16x8*)(MU + r * 512 + col);
  }
  const int cc = tid >> 3, seg = tid & 7;
  const long row0 = (long)blockIdx.x * 16;
  __syncthreads();
  for (int rr = 0; rr < 16; rr++){
    const long row = row0 + rr;
    const uint32_t u = ((const uint32_t*)(X + row * 512))[tid];
    const float aa = bflo(u), bb = bfhi(u);
    xs[2 * tid] = aa; xs[2 * tid + 1] = bb;
    float sq = aa * aa + bb * bb;
#pragma unroll
    for (int m = 1; m < 64; m <<= 1) sq += __shfl_xor(sq, m);
    if (lane == 0) red[wid] = sq;
    __syncthreads();
    const float xn = red[0] + red[1] + red[2] + red[3];
    float p = 0.f;
#pragma unroll
    for (int jj = 0; jj < 8; jj++){
      const int col = jj * 64 + seg * 8;
      bf16x8 m8 = *(const bf16x8*)&mus[cc][col];
      const float* xv = &xs[col];
#pragma unroll
      for (int e = 0; e < 8; e++) p += xv[e] * (float)m8[e];
    }
#pragma unroll
    for (int m = 1; m < 8; m <<= 1) p += __shfl_xor(p, m);
    if (seg == 0) dots[cc] = p;
    __syncthreads();
    if (tid < 32){
      const float dist = xn + munorm[tid] - 2.f * dots[tid];
      const float lg = -dist * 0.1f;
      float mx = lg;
#pragma unroll
      for (int m = 1; m < 32; m <<= 1) mx = fmaxf(mx, __shfl_xor(mx, m, 32));
      const float z = __expf(lg - mx);
      float s = z;
#pragma unroll
      for (int m = 1; m < 32; m <<= 1) s += __shfl_xor(s, m, 32);
      out[row * 32 + tid] = logf(z / s + EPSF);
    }
    __syncthreads();
  }
}

// ---------------------------------------------------------------------------
__global__ __launch_bounds__(256)
void k_hmm(const float* __restrict__ lza, const float* __restrict__ pi,
           const float* __restrict__ A, float* __restrict__ cp, float* __restrict__ ent)
{
  __shared__ float As[32][33];
  const int tid = threadIdx.x;
  for (int i = tid; i < 1024; i += 256) As[i >> 5][i & 31] = A[i];
  __syncthreads();
  const int j = tid & 31;
  const long n = (long)blockIdx.x * 8 + (tid >> 5);
  const float* lz = lza + n * 2048;

  float c = logf(pi[j] + EPSF) + lz[j];
  {
    float mx = c;
#pragma unroll
    for (int m = 1; m < 32; m <<= 1) mx = fmaxf(mx, __shfl_xor(mx, m, 32));
    float z = __expf(c - mx), s = z;
#pragma unroll
    for (int m = 1; m < 32; m <<= 1) s += __shfl_xor(s, m, 32);
    c = z / s;
  }
  cp[n * 2048 + j] = c;
  float ea = -c * logf(c + EPSF);

  for (int p = 1; p < 64; p++){
    float y = 0.f;
#pragma unroll
    for (int i = 0; i < 32; i++) y += __shfl(c, i, 32) * As[i][j];
    float t = logf(y + EPSF) + lz[p * 32 + j];
    float mx = t;
#pragma unroll
    for (int m = 1; m < 32; m <<= 1) mx = fmaxf(mx, __shfl_xor(mx, m, 32));
    float z = __expf(t - mx), s = z;
#pragma unroll
    for (int m = 1; m < 32; m <<= 1) s += __shfl_xor(s, m, 32);
    c = z / s;
    cp[n * 2048 + p * 32 + j] = c;
    ea += -c * logf(c + EPSF);
  }
#pragma unroll
  for (int m = 1; m < 32; m <<= 1) ea += __shfl_xor(ea, m, 32);
  if (j == 0) atomicAdd(ent, ea * (1.f / 131072.f));
}

// ---------------------------------------------------------------------------
extern "C" void kernel_launch(void* const* d_in, const int* in_sizes, int n_in,
                              void* d_out, int out_size, void* d_ws, size_t ws_size,
                              hipStream_t stream)
{
  (void)in_sizes; (void)n_in; (void)out_size; (void)ws_size;
  const float* in_series = (const float*)d_in[0];
  const float* pi    = (const float*)d_in[1];
  const float* Amat  = (const float*)d_in[2];
  const float* qkv_w = (const float*)d_in[3];
  const float* qkv_b = (const float*)d_in[4];
  const float* out_w = (const float*)d_in[5];
  const float* out_b = (const float*)d_in[6];
  const float* ln1_w = (const float*)d_in[7];
  const float* ln1_b = (const float*)d_in[8];
  const float* ff1_w = (const float*)d_in[9];
  const float* ff1_b = (const float*)d_in[10];
  const float* ff2_w = (const float*)d_in[11];
  const float* ff2_b = (const float*)d_in[12];
  const float* ln2_w = (const float*)d_in[13];
  const float* ln2_b = (const float*)d_in[14];
  const float* mus   = (const float*)d_in[15];

  char* ws = (char*)d_ws;
  bf16* region0 = (bf16*)(ws);                         // 512MB: qkv / ffmid
  bf16* xb      = (bf16*)(ws + 536870912L);            // 128MB
  bf16* oproj   = (bf16*)(ws + 671088640L);            // 128MB
  bf16* w_qkv   = (bf16*)(ws + 805306368L);
  bf16* w_out   = (bf16*)(ws + 810024960L);
  bf16* w_ff1   = (bf16*)(ws + 811597824L);
  bf16* w_ff2   = (bf16*)(ws + 817889280L);
  bf16* mubf    = (bf16*)(ws + 824180736L);
  float* munorm = (float*)(ws + 824213504L);
  float* logza  = (float*)(ws);                        // aliases region0

  float* out_f = (float*)d_out;
  float* cp    = out_f;
  float* emb   = out_f + 4194304L;
  float* o_pi  = out_f + 71303168L;
  float* o_A   = out_f + 71303200L;
  float* o_ent = out_f + 71304224L;

  k_f2bf<<<8192, 256, 0, stream>>>(in_series, xb, 67108864L);
  k_f2bf<<<1024, 256, 0, stream>>>(qkv_w, w_qkv, 2359296L);
  k_f2bf<<<1024, 256, 0, stream>>>(out_w, w_out, 786432L);
  k_f2bf<<<1024, 256, 0, stream>>>(ff1_w, w_ff1, 3145728L);
  k_f2bf<<<1024, 256, 0, stream>>>(ff2_w, w_ff2, 3145728L);
  k_mu<<<32, 256, 0, stream>>>(mus, mubf, munorm);

  for (int l = 0; l < 3; l++){
    // qkv = x @ qkv_w^T + b   -> region0 [131072][1536]
    gemm256<0><<<3072, 512, 0, stream>>>(xb, 512, w_qkv + (long)l * 786432L,
                                         qkv_b + (long)l * 1536, region0, 512, 6);
    attention<<<16384, 256, 0, stream>>>(region0);
    // o @ out_w^T + b -> oproj
    gemm256<0><<<1024, 512, 0, stream>>>(region0, 1536, w_out + (long)l * 262144L,
                                         out_b + (long)l * 512, oproj, 512, 2);
    resid_ln<<<32768, 256, 0, stream>>>(xb, oproj, ln1_w + (long)l * 512,
                                        ln1_b + (long)l * 512, xb, nullptr);
    // ffmid = relu(x @ ff1_w^T + b) -> region0 [131072][2048]
    gemm256<1><<<4096, 512, 0, stream>>>(xb, 512, w_ff1 + (long)l * 1048576L,
                                         ff1_b + (long)l * 2048, region0, 512, 8);
    // ffout = ffmid @ ff2_w^T + b -> oproj
    gemm256<0><<<1024, 512, 0, stream>>>(region0, 2048, w_ff2 + (long)l * 1048576L,
                                         ff2_b + (long)l * 512, oproj, 2048, 2);
    // last layer: fuse f32 emb_ts output into the LN
    resid_ln<<<32768, 256, 0, stream>>>(xb, oproj, ln2_w + (long)l * 512,
                                        ln2_b + (long)l * 512, xb,
                                        (l == 2) ? emb : nullptr);
  }

  cluster_logza<<<8192, 256, 0, stream>>>(xb, mubf, munorm, logza);
  hipMemsetAsync(o_ent, 0, 4, stream);
  k_hmm<<<256, 256, 0, stream>>>(logza, pi, Amat, cp, o_ent);
  hipMemcpyAsync(o_pi, pi, 32 * sizeof(float), hipMemcpyDeviceToDevice, stream);
  hipMemcpyAsync(o_A, Amat, 1024 * sizeof(float), hipMemcpyDeviceToDevice, stream);
}